// Round 2
// baseline (20.179 us; speedup 1.0000x reference)
//
#include <hip/hip_runtime.h>

#define NBEST 50
#define SEGS_PER_BLOCK 4   // 4 waves of 64 per block, one segment per wave
#define MARGIN 0.1f

// Kernel 1: one wavefront per segment, no gather, no LDS broadcast.
// Lane j loads seg[j] and werRank[j] coalesced; the rank permutation is
// applied in-register with one ds_bpermute (__shfl with variable index):
//   r_j = seg[werRank[j]] = value held by lane werRank[j].
// Broadcast of r_k uses v_readlane (constant lane -> SGPR operand).
__global__ void __launch_bounds__(256)
margin_partial_kernel(const float* __restrict__ scores,
                      const int* __restrict__ werRank,
                      float* __restrict__ partials,
                      int B) {
    const int wave = threadIdx.x >> 6;   // 0..3
    const int lane = threadIdx.x & 63;   // 0..63
    const int seg  = blockIdx.x * SEGS_PER_BLOCK + wave;

    __shared__ float wsum[SEGS_PER_BLOCK];

    float s  = 0.0f;
    int   wr = 0;
    if (seg < B && lane < NBEST) {
        const int base = seg * NBEST;
        s  = scores[base + lane];    // coalesced
        wr = werRank[base + lane];   // coalesced
    }
    // lane j <- score of lane werRank[j]  (in-register permutation)
    const float rj = __shfl(s, wr, 64);

    // acc_j = sum_{k>j} relu(margin - rj + rk);  c is lane-constant
    const float c = MARGIN - rj;
    float acc = 0.0f;
    #pragma unroll
    for (int k = 1; k < NBEST; ++k) {
        const float rk = __uint_as_float(
            __builtin_amdgcn_readlane(__float_as_uint(rj), k));  // SGPR broadcast
        const float d = fmaxf(c + rk, 0.0f);
        acc += (lane < k) ? d : 0.0f;
    }
    // mean over (N-1-j) negatives; rank N-1 has none.
    float val = (seg < B && lane < NBEST - 1)
                    ? acc / (float)(NBEST - 1 - lane)
                    : 0.0f;

    // 64-lane butterfly reduction
    #pragma unroll
    for (int off = 32; off >= 1; off >>= 1)
        val += __shfl_xor(val, off, 64);

    if (lane == 0) wsum[wave] = val;
    __syncthreads();

    if (threadIdx.x == 0) {
        float t = 0.0f;
        #pragma unroll
        for (int w = 0; w < SEGS_PER_BLOCK; ++w) t += wsum[w];
        partials[blockIdx.x] = t;
    }
}

// Kernel 2: one wavefront, float4 loads, no barriers.
// n is guaranteed a multiple of 256 here (4096 partials).
__global__ void __launch_bounds__(64)
margin_reduce_kernel(const float* __restrict__ partials,
                     int n, float* __restrict__ out) {
    const int lane = threadIdx.x & 63;
    const float4* p4 = (const float4*)partials;
    const int n4 = n >> 2;
    float sum = 0.0f;
    for (int i = lane; i < n4; i += 64) {
        float4 v = p4[i];
        sum += (v.x + v.y) + (v.z + v.w);
    }
    #pragma unroll
    for (int off = 32; off >= 1; off >>= 1)
        sum += __shfl_xor(sum, off, 64);
    if (lane == 0) out[0] = sum;
}

extern "C" void kernel_launch(void* const* d_in, const int* in_sizes, int n_in,
                              void* d_out, int out_size, void* d_ws, size_t ws_size,
                              hipStream_t stream) {
    const float* scores   = (const float*)d_in[0];
    const int*   werRank  = (const int*)d_in[1];
    float*       out      = (float*)d_out;
    float*       partials = (float*)d_ws;   // grid1 floats (16 KB) << ws_size

    const int B = in_sizes[0] / NBEST;      // 16384
    const int grid1 = (B + SEGS_PER_BLOCK - 1) / SEGS_PER_BLOCK;  // 4096

    margin_partial_kernel<<<grid1, SEGS_PER_BLOCK * 64, 0, stream>>>(
        scores, werRank, partials, B);
    margin_reduce_kernel<<<1, 64, 0, stream>>>(partials, grid1, out);
}